// Round 9
// baseline (227.089 us; speedup 1.0000x reference)
//
#include <hip/hip_runtime.h>

typedef unsigned short u16;
typedef __bf16 bfx8 __attribute__((ext_vector_type(8)));
typedef float f32x4 __attribute__((ext_vector_type(4)));
typedef float f32x16 __attribute__((ext_vector_type(16)));

#define MFMA16(a,b,c) __builtin_amdgcn_mfma_f32_16x16x32_bf16(a,b,c,0,0,0)
#define MFMA32(a,b,c) __builtin_amdgcn_mfma_f32_32x32x16_bf16(a,b,c,0,0,0)

// ---------- helpers ----------
__device__ __forceinline__ u16 f2bf(float f) {
  union { float f; unsigned u; } v; v.f = f;
  unsigned r = v.u + 0x7fffu + ((v.u >> 16) & 1u);   // RNE
  return (u16)(r >> 16);
}

__device__ __forceinline__ unsigned cvtpk(float lo, float hi) {
  unsigned r;
  asm("v_cvt_pk_bf16_f32 %0, %1, %2" : "=v"(r) : "v"(lo), "v"(hi));
  return r;
}

__device__ __forceinline__ void swap32(unsigned &a, unsigned &b) {
  asm("v_permlane32_swap_b32 %0, %1" : "+v"(a), "+v"(b));
}

__device__ __forceinline__ void gld16(const void* g, void* l) {
  __builtin_amdgcn_global_load_lds(
      (const __attribute__((address_space(1))) unsigned int*)g,
      (__attribute__((address_space(3))) unsigned int*)l, 16, 0, 0);
}

// ============================================================================
// Fragment-linear layouts:
//   Xf[(rowgrp * KT + kgrp) * 512 + lane * 8 + j]
//     holds X[rowgrp*16 + (lane&15)][kgrp*32 + (lane>>4)*8 + j]   (KT = K/32)
// ============================================================================

// ---------- x [4096][2048] f32 -> Af fragment-linear bf16 ----------
__global__ void afrag_k(const float* __restrict__ in, u16* __restrict__ Af) {
  int i = blockIdx.x * 256 + threadIdx.x;
  int sm = i >> 8, d0 = (i & 255) * 8;
  const float* p = in + (size_t)sm * 2048 + d0;
  float4 a = *(const float4*)p;
  float4 b = *(const float4*)(p + 4);
  union { u16 h[8]; uint4 u; } o;
  o.h[0]=f2bf(a.x); o.h[1]=f2bf(a.y); o.h[2]=f2bf(a.z); o.h[3]=f2bf(a.w);
  o.h[4]=f2bf(b.x); o.h[5]=f2bf(b.y); o.h[6]=f2bf(b.z); o.h[7]=f2bf(b.w);
  int mt = sm >> 4, kt = d0 >> 5, lp = (sm & 15) + ((d0 >> 3) & 3) * 16;
  *(uint4*)(Af + ((size_t)(mt * 64 + kt) * 512 + lp * 8)) = o.u;
}

// ---------- W [2048 K][N] f32 -> Bf fragment-linear bf16 (B^T[n][k]) ----------
__global__ void bfrag_k(const float* __restrict__ W, u16* __restrict__ Bf,
                        int N, int ntoff) {
  __shared__ float tile[32][72];
  int nb = blockIdx.x, kb = blockIdx.y;
  int t = threadIdx.x;
  int r = t >> 3, c8 = (t & 7) * 8;
  const float* src = W + (size_t)(kb * 32 + r) * N + nb * 64 + c8;
  *(float4*)&tile[r][c8]     = *(const float4*)src;
  *(float4*)&tile[r][c8 + 4] = *(const float4*)(src + 4);
  __syncthreads();
  int fb = t >> 6, l = t & 63;
  int nn = fb * 16 + (l & 15), k0 = (l >> 4) * 8;
  union { u16 h[8]; uint4 u; } o;
  #pragma unroll
  for (int j = 0; j < 8; j++) o.h[j] = f2bf(tile[k0 + j][nn]);
  *(uint4*)(Bf + ((size_t)((ntoff + nb * 4 + fb) * 64 + kb) * 512 + l * 8)) = o.u;
}

// ============================================================================
// QKV GEMM 128x256, 8 waves, BK=32, counted vmcnt — FUSED RoPE + frag epilogue
// ============================================================================
__global__ __launch_bounds__(512, 4) void gemm_qkv(
    const u16* __restrict__ Af, const u16* __restrict__ Bf,
    const float* __restrict__ cosT, const float* __restrict__ sinT,
    u16* __restrict__ Qf, u16* __restrict__ Kf, u16* __restrict__ Vf) {
  __shared__ u16 lds[2 * 24 * 512];
  const int tid = threadIdx.x, lane = tid & 63, w = tid >> 6;
  const int wm = w >> 2, wn = w & 3;
  const int lrow = lane & 15, lg = lane >> 4;
  const int nwg = gridDim.x;
  const int per = nwg >> 3;
  const int swz = ((int)blockIdx.x & 7) * per + ((int)blockIdx.x >> 3);
  const int bm = swz / 12, bn = swz % 12;
  const int bm8 = bm * 8, bn16 = bn * 16;
  const int KT = 64;

  f32x4 acc[4][4] = {};
  u16* buf0 = lds;
  u16* buf1 = lds + 24 * 512;

  auto stageB = [&](int s, u16* dst) {
    #pragma unroll
    for (int j = 0; j < 2; j++) {
      int ng = w * 2 + j;
      gld16(Bf + ((size_t)(bn16 + ng) * KT + s) * 512 + lane * 8,
            dst + (8 + ng) * 512);
    }
  };
  auto stageA = [&](int s, u16* dst) {
    gld16(Af + ((size_t)(bm8 + w) * KT + s) * 512 + lane * 8,
          dst + w * 512);
  };

  stageB(0, buf0); stageA(0, buf0);
  stageB(1, buf1); stageA(1, buf1);
  asm volatile("s_waitcnt vmcnt(3)" ::: "memory");
  __builtin_amdgcn_s_barrier();

  bfx8 ar[2], br[4];
  for (int t = 0; t < KT; t++) {
    u16* rb = (t & 1) ? buf1 : buf0;
    const int s2 = (t + 2 < KT) ? t + 2 : 0;
    #pragma unroll
    for (int i = 0; i < 2; i++)
      ar[i] = *(const bfx8*)(rb + (wm * 4 + i) * 512 + lane * 8);
    #pragma unroll
    for (int j = 0; j < 4; j++)
      br[j] = *(const bfx8*)(rb + (8 + wn * 4 + j) * 512 + lane * 8);
    asm volatile("s_waitcnt lgkmcnt(0)" ::: "memory");
    __builtin_amdgcn_s_barrier();
    stageB(s2, rb);
    __builtin_amdgcn_s_setprio(1);
    #pragma unroll
    for (int i = 0; i < 2; i++)
      #pragma unroll
      for (int j = 0; j < 4; j++)
        acc[i][j] = MFMA16(ar[i], br[j], acc[i][j]);
    __builtin_amdgcn_s_setprio(0);
    __builtin_amdgcn_s_barrier();
    #pragma unroll
    for (int i = 0; i < 2; i++)
      ar[i] = *(const bfx8*)(rb + (wm * 4 + 2 + i) * 512 + lane * 8);
    asm volatile("s_waitcnt lgkmcnt(0)" ::: "memory");
    __builtin_amdgcn_s_barrier();
    stageA(s2, rb);
    __builtin_amdgcn_s_setprio(1);
    #pragma unroll
    for (int i = 0; i < 2; i++)
      #pragma unroll
      for (int j = 0; j < 4; j++)
        acc[2 + i][j] = MFMA16(ar[i], br[j], acc[2 + i][j]);
    __builtin_amdgcn_s_setprio(0);
    asm volatile("s_waitcnt vmcnt(3)" ::: "memory");
    __builtin_amdgcn_s_barrier();
  }
  asm volatile("s_waitcnt vmcnt(0)" ::: "memory");
  __builtin_amdgcn_s_barrier();

  // ---------------- fused epilogue ----------------
  const int hh = bn * 4 + wn;               // global head slot [0,48)
  const int m0 = bm * 128 + wm * 64;
  u16* otw = lds + w * 2048;
  char* otb = (char*)otw;

  #pragma unroll
  for (int half = 0; half < 2; half++) {
    const int rowbase = m0 + half * 32;
    const int bb = rowbase >> 11;
    const int s0 = rowbase & 2047;
    if (hh < 40) {
      const float qsc = (hh < 32) ? 0.18033688f : 1.0f;
      #pragma unroll
      for (int mgl = 0; mgl < 2; mgl++) {
        const int mg = half * 2 + mgl;
        #pragma unroll
        for (int ng = 0; ng < 2; ng++) {
          const int d1 = ng * 16 + lrow;
          #pragma unroll
          for (int r = 0; r < 4; r++) {
            int s = s0 + mgl * 16 + lg * 4 + r;
            float a  = acc[mg][ng][r];
            float a2 = acc[mg][ng + 2][r];
            float c1 = cosT[s * 64 + d1],      s1v = sinT[s * 64 + d1];
            float c2 = cosT[s * 64 + d1 + 32], s2v = sinT[s * 64 + d1 + 32];
            float o1 = (a * c1 - a2 * s1v) * qsc;
            float o2 = (a2 * c2 + a * s2v) * qsc;
            int srow = mgl * 16 + lg * 4 + r;
            int swzb = (srow & 7) << 4;
            *(u16*)(otb + ((srow * 128 + d1 * 2) ^ swzb)) = f2bf(o1);
            *(u16*)(otb + ((srow * 128 + (d1 + 32) * 2) ^ swzb)) = f2bf(o2);
          }
        }
      }
      const int qt = s0 >> 5;
      u16* dst = (hh < 32)
          ? Qf + ((size_t)(bb * 32 + hh) * 64 + qt) * 2048
          : Kf + ((size_t)(bb * 8 + (hh - 32)) * 64 + qt) * 2048;
      const int srw = lane & 31;
      const int d0 = (lane >> 5) * 8;
      #pragma unroll
      for (int ks = 0; ks < 4; ks++) {
        int byte = ((srw * 128 + (ks * 16 + d0) * 2)) ^ ((srw & 7) << 4);
        uint4 v = *(uint4*)(otb + byte);
        *(uint4*)(dst + ks * 512 + lane * 8) = v;
      }
    } else {
      #pragma unroll
      for (int mgl = 0; mgl < 2; mgl++) {
        const int mg = half * 2 + mgl;
        #pragma unroll
        for (int ng = 0; ng < 4; ng++) {
          const int d = ng * 16 + lrow;
          #pragma unroll
          for (int r = 0; r < 4; r++) {
            int srow = mgl * 16 + lg * 4 + r;
            *(u16*)(otb + ((srow * 128 + d * 2) ^ ((srow & 7) << 4))) =
                f2bf(acc[mg][ng][r]);
          }
        }
      }
      const int kt = s0 >> 6;
      const int g = hh - 40;
      u16* dst = Vf + ((size_t)(bb * 8 + g) * 32 + kt) * 4096;
      const int d = lane & 31;
      const int hi8 = (lane >> 5) * 8;
      #pragma unroll
      for (int ks2 = 0; ks2 < 2; ks2++) {
        const int ks = half * 2 + ks2;
        #pragma unroll
        for (int sub = 0; sub < 2; sub++) {
          const int dd = sub * 32 + d;
          union { u16 h[8]; uint4 u; } o;
          #pragma unroll
          for (int j = 0; j < 8; j++) {
            int srow = ks2 * 16 + hi8 + j;
            o.h[j] = *(u16*)(otb + ((srow * 128 + dd * 2) ^ ((srow & 7) << 4)));
          }
          *(uint4*)(dst + (sub * 4 + ks) * 512 + lane * 8) = o.u;
        }
      }
    }
    __builtin_amdgcn_s_barrier();
  }
}

// ============================================================================
// 128x256 bf16 GEMM (output projection), f32 C write
// ============================================================================
__global__ __launch_bounds__(512, 4) void gemm8p(
    const u16* __restrict__ Af, const u16* __restrict__ Bf,
    float* __restrict__ C, int N, int KT, int nbx) {
  __shared__ u16 lds[2 * 24 * 512];
  const int tid = threadIdx.x, lane = tid & 63, w = tid >> 6;
  const int wm = w >> 2, wn = w & 3;
  const int lrow = lane & 15, lg = lane >> 4;
  const int nwg = gridDim.x;
  const int per = nwg >> 3;
  const int swz = ((int)blockIdx.x & 7) * per + ((int)blockIdx.x >> 3);
  const int bm = swz / nbx, bn = swz % nbx;
  const int bm8 = bm * 8, bn16 = bn * 16;
  const int T = KT;

  f32x4 acc[4][4] = {};
  u16* buf0 = lds;
  u16* buf1 = lds + 24 * 512;

  auto stageB = [&](int s, u16* dst) {
    #pragma unroll
    for (int j = 0; j < 2; j++) {
      int ng = w * 2 + j;
      gld16(Bf + ((size_t)(bn16 + ng) * KT + s) * 512 + lane * 8,
            dst + (8 + ng) * 512);
    }
  };
  auto stageA = [&](int s, u16* dst) {
    gld16(Af + ((size_t)(bm8 + w) * KT + s) * 512 + lane * 8,
          dst + w * 512);
  };

  stageB(0, buf0); stageA(0, buf0);
  stageB(1, buf1); stageA(1, buf1);
  asm volatile("s_waitcnt vmcnt(3)" ::: "memory");
  __builtin_amdgcn_s_barrier();

  bfx8 ar[2], br[4];
  for (int t = 0; t < T; t++) {
    u16* rb = (t & 1) ? buf1 : buf0;
    const int s2 = (t + 2 < T) ? t + 2 : 0;
    #pragma unroll
    for (int i = 0; i < 2; i++)
      ar[i] = *(const bfx8*)(rb + (wm * 4 + i) * 512 + lane * 8);
    #pragma unroll
    for (int j = 0; j < 4; j++)
      br[j] = *(const bfx8*)(rb + (8 + wn * 4 + j) * 512 + lane * 8);
    asm volatile("s_waitcnt lgkmcnt(0)" ::: "memory");
    __builtin_amdgcn_s_barrier();
    stageB(s2, rb);
    __builtin_amdgcn_s_setprio(1);
    #pragma unroll
    for (int i = 0; i < 2; i++)
      #pragma unroll
      for (int j = 0; j < 4; j++)
        acc[i][j] = MFMA16(ar[i], br[j], acc[i][j]);
    __builtin_amdgcn_s_setprio(0);
    __builtin_amdgcn_s_barrier();
    #pragma unroll
    for (int i = 0; i < 2; i++)
      ar[i] = *(const bfx8*)(rb + (wm * 4 + 2 + i) * 512 + lane * 8);
    asm volatile("s_waitcnt lgkmcnt(0)" ::: "memory");
    __builtin_amdgcn_s_barrier();
    stageA(s2, rb);
    __builtin_amdgcn_s_setprio(1);
    #pragma unroll
    for (int i = 0; i < 2; i++)
      #pragma unroll
      for (int j = 0; j < 4; j++)
        acc[2 + i][j] = MFMA16(ar[i], br[j], acc[2 + i][j]);
    __builtin_amdgcn_s_setprio(0);
    asm volatile("s_waitcnt vmcnt(3)" ::: "memory");
    __builtin_amdgcn_s_barrier();
  }
  asm volatile("s_waitcnt vmcnt(0)" ::: "memory");

  const int m0 = bm * 128 + wm * 64, n0 = bn * 256 + wn * 64;
  #pragma unroll
  for (int mg = 0; mg < 4; mg++) {
    int row = m0 + mg * 16 + lg * 4;
    #pragma unroll
    for (int ng = 0; ng < 4; ng++) {
      int col = n0 + ng * 16 + lrow;
      float* cp = C + (size_t)row * N + col;
      #pragma unroll
      for (int r = 0; r < 4; r++) cp[(size_t)r * N] = acc[mg][ng][r];
    }
  }
}

// ---------- causal flash attention, GQA — K-split pairs @ 3 waves/SIMD ----------
// grid (32, H, B), 256 thr. Block = pair {63-qrA, qrA}; wave (pr,sub): pr picks
// q-tile, sub picks K-range half. No kn prefetch (regs fit 170 budget); TLP
// hides load latency at 3 waves/SIMD. LDS merge of (m,l,O); scale pre-folded.
__global__ __launch_bounds__(256, 3) void attn_k(
    const u16* __restrict__ Qf, const u16* __restrict__ Kf,
    const u16* __restrict__ Vf, u16* __restrict__ Aof)
{
  __shared__ float mO[2][32 * 64];
  __shared__ float mm[2][64], ml[2][64];
  __shared__ u16 ot[2][32 * 64];
  const int tid = threadIdx.x, lane = tid & 63, w = tid >> 6;
  const int h = blockIdx.y, b = blockIdx.z;
  const int kvh = h >> 2;
  const int ql = lane & 31, hi = lane >> 5;
  const int qrA = blockIdx.x;             // [0,32)
  const int pr = w >> 1, sub = w & 1;
  const int qr = pr ? qrA : 63 - qrA;
  const int q0 = qr * 32;
  const int qg = q0 + ql;
  const int nkt = qr / 2 + 1;
  const int hf = (nkt + 1) >> 1;
  const int tbeg = sub ? hf : 0;
  const int tend = sub ? nkt : hf;

  const u16* Qh = Qf + (size_t)(b * 32 + h) * 131072;
  const u16* Kp = Kf + (size_t)(b * 8 + kvh) * 131072;
  const u16* Vp = Vf + (size_t)(b * 8 + kvh) * 131072;

  bfx8 qf[4];
  #pragma unroll
  for (int ks = 0; ks < 4; ks++)
    qf[ks] = *(const bfx8*)(Qh + (size_t)qr * 2048 + ks * 512 + lane * 8);

  f32x16 oacc0 = {}, oacc1 = {};
  float m2 = -3.0e38f;
  float lsum = 0.f;

  for (int kt = tbeg; kt < tend; kt++) {
    const int kb = kt * 64;
    bfx8 ka[8];
    #pragma unroll
    for (int i = 0; i < 8; i++)
      ka[i] = *(const bfx8*)(Kp + (size_t)kt * 4096 + i * 512 + lane * 8);
    bfx8 va[8];
    #pragma unroll
    for (int i = 0; i < 8; i++)
      va[i] = *(const bfx8*)(Vp + (size_t)kt * 4096 + i * 512 + lane * 8);
    f32x16 st0 = {}, st1 = {};
    #pragma unroll
    for (int ks = 0; ks < 4; ks++) {
      st0 = MFMA32(ka[ks], qf[ks], st0);
      st1 = MFMA32(ka[4 + ks], qf[ks], st1);
    }
    if (kt == nkt - 1) {
      #pragma unroll
      for (int r = 0; r < 16; r++) {
        int crow = (r & 3) + 8 * (r >> 2) + 4 * hi;
        if (kb + crow > qg) st0[r] = -3.0e38f;
        if (kb + 32 + crow > qg) st1[r] = -3.0e38f;
      }
    }
    float mx[16];
    #pragma unroll
    for (int r = 0; r < 16; r++) mx[r] = fmaxf(st0[r], st1[r]);
    #pragma unroll
    for (int s = 8; s > 0; s >>= 1)
      #pragma unroll
      for (int r = 0; r < s; r++) mx[r] = fmaxf(mx[r], mx[r + s]);
    float tm = fmaxf(mx[0], __shfl_xor(mx[0], 32));
    float mnew = fmaxf(m2, tm);
    if (!__all(tm <= m2 + 8.0f)) {
      float corr = exp2f(m2 - mnew);
      lsum *= corr;
      #pragma unroll
      for (int i = 0; i < 16; i++) { oacc0[i] *= corr; oacc1[i] *= corr; }
      m2 = mnew;
    }
    #pragma unroll
    for (int r = 0; r < 16; r++) { st0[r] = exp2f(st0[r] - m2); }
    #pragma unroll
    for (int r = 0; r < 16; r++) { st1[r] = exp2f(st1[r] - m2); }
    float sm[16];
    #pragma unroll
    for (int r = 0; r < 16; r++) sm[r] = st0[r] + st1[r];
    #pragma unroll
    for (int s = 8; s > 0; s >>= 1)
      #pragma unroll
      for (int r = 0; r < s; r++) sm[r] += sm[r + s];
    lsum += sm[0];
    bfx8 pb[4];
    #pragma unroll
    for (int ks = 0; ks < 4; ks++) {
      int o = (ks & 1) * 8;
      unsigned X = cvtpk(ks < 2 ? st0[o + 0] : st1[o + 0], ks < 2 ? st0[o + 1] : st1[o + 1]);
      unsigned Z = cvtpk(ks < 2 ? st0[o + 2] : st1[o + 2], ks < 2 ? st0[o + 3] : st1[o + 3]);
      unsigned Y = cvtpk(ks < 2 ? st0[o + 4] : st1[o + 4], ks < 2 ? st0[o + 5] : st1[o + 5]);
      unsigned W = cvtpk(ks < 2 ? st0[o + 6] : st1[o + 6], ks < 2 ? st0[o + 7] : st1[o + 7]);
      swap32(X, Y);
      swap32(Z, W);
      union { unsigned u[4]; bfx8 v; } uu;
      uu.u[0] = X; uu.u[1] = Z; uu.u[2] = Y; uu.u[3] = W;
      pb[ks] = uu.v;
    }
    #pragma unroll
    for (int ks = 0; ks < 4; ks++) {
      oacc0 = MFMA32(va[ks], pb[ks], oacc0);
      oacc1 = MFMA32(va[4 + ks], pb[ks], oacc1);
    }
  }

  // ---- publish second-half state, merge in first-half wave ----
  if (sub) {
    #pragma unroll
    for (int i = 0; i < 16; i++) mO[pr][i * 64 + lane] = oacc0[i];
    #pragma unroll
    for (int i = 0; i < 16; i++) mO[pr][(16 + i) * 64 + lane] = oacc1[i];
    mm[pr][lane] = m2;
    ml[pr][lane] = lsum;
  }
  __syncthreads();
  if (!sub) {
    float mB = mm[pr][lane], lB = ml[pr][lane];
    float mn = fmaxf(m2, mB);
    float cA = exp2f(m2 - mn), cB = exp2f(mB - mn);
    lsum = lsum * cA + lB * cB;
    #pragma unroll
    for (int i = 0; i < 16; i++) oacc0[i] = oacc0[i] * cA + mO[pr][i * 64 + lane] * cB;
    #pragma unroll
    for (int i = 0; i < 16; i++) oacc1[i] = oacc1[i] * cA + mO[pr][(16 + i) * 64 + lane] * cB;
    lsum += __shfl_xor(lsum, 32);
    float inv = 1.f / lsum;
    u16* my = ot[pr];
    #pragma unroll
    for (int dt = 0; dt < 2; dt++) {
      #pragma unroll
      for (int g = 0; g < 4; g++) {
        float a0 = (dt ? oacc1[g*4+0] : oacc0[g*4+0]) * inv;
        float a1 = (dt ? oacc1[g*4+1] : oacc0[g*4+1]) * inv;
        float a2 = (dt ? oacc1[g*4+2] : oacc0[g*4+2]) * inv;
        float a3 = (dt ? oacc1[g*4+3] : oacc0[g*4+3]) * inv;
        unsigned w0 = cvtpk(a0, a1), w1 = cvtpk(a2, a3);
        int d = dt * 32 + g * 8 + 4 * hi;
        int byte = (ql * 128 + d * 2) ^ ((ql & 7) << 4);
        *(uint2*)((char*)my + byte) = make_uint2(w0, w1);
      }
    }
    #pragma unroll
    for (int rr = 0; rr < 4; rr++) {
      int q = rr * 8 + (lane >> 3);
      int dk = (lane & 7) * 8;
      int byte = (q * 128 + dk * 2) ^ ((q & 7) << 4);
      uint4 val = *(uint4*)((char*)my + byte);
      int mt = b * 128 + qr * 2 + (q >> 4);
      int ktg = h * 2 + (dk >> 5);
      int lp = (q & 15) + ((dk >> 3) & 3) * 16;
      *(uint4*)(Aof + ((size_t)(mt * 64 + ktg) * 512 + lp * 8)) = val;
    }
  }
}

// ---------- launch ----------
extern "C" void kernel_launch(void* const* d_in, const int* in_sizes, int n_in,
                              void* d_out, int out_size, void* d_ws, size_t ws_size,
                              hipStream_t stream) {
  const float* x    = (const float*)d_in[0];
  const float* cosT = (const float*)d_in[1];
  const float* sinT = (const float*)d_in[2];
  const float* Wq   = (const float*)d_in[3];
  const float* Wk   = (const float*)d_in[4];
  const float* Wv   = (const float*)d_in[5];
  const float* Wo   = (const float*)d_in[6];
  float* out = (float*)d_out;
  char* ws = (char*)d_ws;

  u16* Af   = (u16*)(ws);                    // 16 MB (x frags)
  u16* Bqkv = (u16*)(ws + 16777216);         // 12 MB
  u16* Bwo  = (u16*)(ws + 29360128);         //  8 MB
  u16* Qf   = (u16*)(ws + 37748736);         // 16 MB
  u16* Kf   = (u16*)(ws + 54525952);         //  4 MB
  u16* Vf   = (u16*)(ws + 58720256);         //  4 MB
  u16* Aof  = (u16*)(ws + 62914560);         // 16 MB

  afrag_k<<<4096, 256, 0, stream>>>(x, Af);
  bfrag_k<<<dim3(32, 64), 256, 0, stream>>>(Wq, Bqkv, 2048, 0);
  bfrag_k<<<dim3(8, 64), 256, 0, stream>>>(Wk, Bqkv, 512, 128);
  bfrag_k<<<dim3(8, 64), 256, 0, stream>>>(Wv, Bqkv, 512, 160);
  bfrag_k<<<dim3(32, 64), 256, 0, stream>>>(Wo, Bwo, 2048, 0);

  gemm_qkv<<<384, 512, 0, stream>>>(Af, Bqkv, cosT, sinT, Qf, Kf, Vf);

  attn_k<<<dim3(32, 32, 2), 256, 0, stream>>>(Qf, Kf, Vf, Aof);

  gemm8p<<<256, 512, 0, stream>>>(Aof, Bwo, out, 2048, 64, 8);
}

// Round 10
// 199.788 us; speedup vs baseline: 1.1366x; 1.1366x over previous
//
#include <hip/hip_runtime.h>

typedef unsigned short u16;
typedef __bf16 bfx8 __attribute__((ext_vector_type(8)));
typedef float f32x4 __attribute__((ext_vector_type(4)));
typedef float f32x16 __attribute__((ext_vector_type(16)));

#define MFMA16(a,b,c) __builtin_amdgcn_mfma_f32_16x16x32_bf16(a,b,c,0,0,0)
#define MFMA32(a,b,c) __builtin_amdgcn_mfma_f32_32x32x16_bf16(a,b,c,0,0,0)

// ---------- helpers ----------
__device__ __forceinline__ u16 f2bf(float f) {
  union { float f; unsigned u; } v; v.f = f;
  unsigned r = v.u + 0x7fffu + ((v.u >> 16) & 1u);   // RNE
  return (u16)(r >> 16);
}

__device__ __forceinline__ unsigned cvtpk(float lo, float hi) {
  unsigned r;
  asm("v_cvt_pk_bf16_f32 %0, %1, %2" : "=v"(r) : "v"(lo), "v"(hi));
  return r;
}

__device__ __forceinline__ void swap32(unsigned &a, unsigned &b) {
  asm("v_permlane32_swap_b32 %0, %1" : "+v"(a), "+v"(b));
}

__device__ __forceinline__ void gld16(const void* g, void* l) {
  __builtin_amdgcn_global_load_lds(
      (const __attribute__((address_space(1))) unsigned int*)g,
      (__attribute__((address_space(3))) unsigned int*)l, 16, 0, 0);
}

// ============================================================================
// Fragment-linear layouts:
//   Xf[(rowgrp * KT + kgrp) * 512 + lane * 8 + j]
//     holds X[rowgrp*16 + (lane&15)][kgrp*32 + (lane>>4)*8 + j]   (KT = K/32)
// ============================================================================

// ---------- x [4096][2048] f32 -> Af fragment-linear bf16 ----------
__global__ void afrag_k(const float* __restrict__ in, u16* __restrict__ Af) {
  int i = blockIdx.x * 256 + threadIdx.x;
  int sm = i >> 8, d0 = (i & 255) * 8;
  const float* p = in + (size_t)sm * 2048 + d0;
  float4 a = *(const float4*)p;
  float4 b = *(const float4*)(p + 4);
  union { u16 h[8]; uint4 u; } o;
  o.h[0]=f2bf(a.x); o.h[1]=f2bf(a.y); o.h[2]=f2bf(a.z); o.h[3]=f2bf(a.w);
  o.h[4]=f2bf(b.x); o.h[5]=f2bf(b.y); o.h[6]=f2bf(b.z); o.h[7]=f2bf(b.w);
  int mt = sm >> 4, kt = d0 >> 5, lp = (sm & 15) + ((d0 >> 3) & 3) * 16;
  *(uint4*)(Af + ((size_t)(mt * 64 + kt) * 512 + lp * 8)) = o.u;
}

// ---------- W [2048 K][N] f32 -> Bf fragment-linear bf16 (B^T[n][k]) ----------
__global__ void bfrag_k(const float* __restrict__ W, u16* __restrict__ Bf,
                        int N, int ntoff) {
  __shared__ float tile[32][72];
  int nb = blockIdx.x, kb = blockIdx.y;
  int t = threadIdx.x;
  int r = t >> 3, c8 = (t & 7) * 8;
  const float* src = W + (size_t)(kb * 32 + r) * N + nb * 64 + c8;
  *(float4*)&tile[r][c8]     = *(const float4*)src;
  *(float4*)&tile[r][c8 + 4] = *(const float4*)(src + 4);
  __syncthreads();
  int fb = t >> 6, l = t & 63;
  int nn = fb * 16 + (l & 15), k0 = (l >> 4) * 8;
  union { u16 h[8]; uint4 u; } o;
  #pragma unroll
  for (int j = 0; j < 8; j++) o.h[j] = f2bf(tile[k0 + j][nn]);
  *(uint4*)(Bf + ((size_t)((ntoff + nb * 4 + fb) * 64 + kb) * 512 + l * 8)) = o.u;
}

// ============================================================================
// QKV GEMM 128x256, 8 waves, BK=32, counted vmcnt — FUSED RoPE + frag epilogue
// ============================================================================
__global__ __launch_bounds__(512, 4) void gemm_qkv(
    const u16* __restrict__ Af, const u16* __restrict__ Bf,
    const float* __restrict__ cosT, const float* __restrict__ sinT,
    u16* __restrict__ Qf, u16* __restrict__ Kf, u16* __restrict__ Vf) {
  __shared__ u16 lds[2 * 24 * 512];
  const int tid = threadIdx.x, lane = tid & 63, w = tid >> 6;
  const int wm = w >> 2, wn = w & 3;
  const int lrow = lane & 15, lg = lane >> 4;
  const int nwg = gridDim.x;
  const int per = nwg >> 3;
  const int swz = ((int)blockIdx.x & 7) * per + ((int)blockIdx.x >> 3);
  const int bm = swz / 12, bn = swz % 12;
  const int bm8 = bm * 8, bn16 = bn * 16;
  const int KT = 64;

  f32x4 acc[4][4] = {};
  u16* buf0 = lds;
  u16* buf1 = lds + 24 * 512;

  auto stageB = [&](int s, u16* dst) {
    #pragma unroll
    for (int j = 0; j < 2; j++) {
      int ng = w * 2 + j;
      gld16(Bf + ((size_t)(bn16 + ng) * KT + s) * 512 + lane * 8,
            dst + (8 + ng) * 512);
    }
  };
  auto stageA = [&](int s, u16* dst) {
    gld16(Af + ((size_t)(bm8 + w) * KT + s) * 512 + lane * 8,
          dst + w * 512);
  };

  stageB(0, buf0); stageA(0, buf0);
  stageB(1, buf1); stageA(1, buf1);
  asm volatile("s_waitcnt vmcnt(3)" ::: "memory");
  __builtin_amdgcn_s_barrier();

  bfx8 ar[2], br[4];
  for (int t = 0; t < KT; t++) {
    u16* rb = (t & 1) ? buf1 : buf0;
    const int s2 = (t + 2 < KT) ? t + 2 : 0;
    #pragma unroll
    for (int i = 0; i < 2; i++)
      ar[i] = *(const bfx8*)(rb + (wm * 4 + i) * 512 + lane * 8);
    #pragma unroll
    for (int j = 0; j < 4; j++)
      br[j] = *(const bfx8*)(rb + (8 + wn * 4 + j) * 512 + lane * 8);
    asm volatile("s_waitcnt lgkmcnt(0)" ::: "memory");
    __builtin_amdgcn_s_barrier();
    stageB(s2, rb);
    __builtin_amdgcn_s_setprio(1);
    #pragma unroll
    for (int i = 0; i < 2; i++)
      #pragma unroll
      for (int j = 0; j < 4; j++)
        acc[i][j] = MFMA16(ar[i], br[j], acc[i][j]);
    __builtin_amdgcn_s_setprio(0);
    __builtin_amdgcn_s_barrier();
    #pragma unroll
    for (int i = 0; i < 2; i++)
      ar[i] = *(const bfx8*)(rb + (wm * 4 + 2 + i) * 512 + lane * 8);
    asm volatile("s_waitcnt lgkmcnt(0)" ::: "memory");
    __builtin_amdgcn_s_barrier();
    stageA(s2, rb);
    __builtin_amdgcn_s_setprio(1);
    #pragma unroll
    for (int i = 0; i < 2; i++)
      #pragma unroll
      for (int j = 0; j < 4; j++)
        acc[2 + i][j] = MFMA16(ar[i], br[j], acc[2 + i][j]);
    __builtin_amdgcn_s_setprio(0);
    asm volatile("s_waitcnt vmcnt(3)" ::: "memory");
    __builtin_amdgcn_s_barrier();
  }
  asm volatile("s_waitcnt vmcnt(0)" ::: "memory");
  __builtin_amdgcn_s_barrier();

  // ---------------- fused epilogue ----------------
  const int hh = bn * 4 + wn;               // global head slot [0,48)
  const int m0 = bm * 128 + wm * 64;
  u16* otw = lds + w * 2048;
  char* otb = (char*)otw;

  #pragma unroll
  for (int half = 0; half < 2; half++) {
    const int rowbase = m0 + half * 32;
    const int bb = rowbase >> 11;
    const int s0 = rowbase & 2047;
    if (hh < 40) {
      const float qsc = (hh < 32) ? 0.18033688f : 1.0f;
      #pragma unroll
      for (int mgl = 0; mgl < 2; mgl++) {
        const int mg = half * 2 + mgl;
        #pragma unroll
        for (int ng = 0; ng < 2; ng++) {
          const int d1 = ng * 16 + lrow;
          #pragma unroll
          for (int r = 0; r < 4; r++) {
            int s = s0 + mgl * 16 + lg * 4 + r;
            float a  = acc[mg][ng][r];
            float a2 = acc[mg][ng + 2][r];
            float c1 = cosT[s * 64 + d1],      s1v = sinT[s * 64 + d1];
            float c2 = cosT[s * 64 + d1 + 32], s2v = sinT[s * 64 + d1 + 32];
            float o1 = (a * c1 - a2 * s1v) * qsc;
            float o2 = (a2 * c2 + a * s2v) * qsc;
            int srow = mgl * 16 + lg * 4 + r;
            int swzb = (srow & 7) << 4;
            *(u16*)(otb + ((srow * 128 + d1 * 2) ^ swzb)) = f2bf(o1);
            *(u16*)(otb + ((srow * 128 + (d1 + 32) * 2) ^ swzb)) = f2bf(o2);
          }
        }
      }
      const int qt = s0 >> 5;
      u16* dst = (hh < 32)
          ? Qf + ((size_t)(bb * 32 + hh) * 64 + qt) * 2048
          : Kf + ((size_t)(bb * 8 + (hh - 32)) * 64 + qt) * 2048;
      const int srw = lane & 31;
      const int d0 = (lane >> 5) * 8;
      #pragma unroll
      for (int ks = 0; ks < 4; ks++) {
        int byte = ((srw * 128 + (ks * 16 + d0) * 2)) ^ ((srw & 7) << 4);
        uint4 v = *(uint4*)(otb + byte);
        *(uint4*)(dst + ks * 512 + lane * 8) = v;
      }
    } else {
      #pragma unroll
      for (int mgl = 0; mgl < 2; mgl++) {
        const int mg = half * 2 + mgl;
        #pragma unroll
        for (int ng = 0; ng < 4; ng++) {
          const int d = ng * 16 + lrow;
          #pragma unroll
          for (int r = 0; r < 4; r++) {
            int srow = mgl * 16 + lg * 4 + r;
            *(u16*)(otb + ((srow * 128 + d * 2) ^ ((srow & 7) << 4))) =
                f2bf(acc[mg][ng][r]);
          }
        }
      }
      const int kt = s0 >> 6;
      const int g = hh - 40;
      u16* dst = Vf + ((size_t)(bb * 8 + g) * 32 + kt) * 4096;
      const int d = lane & 31;
      const int hi8 = (lane >> 5) * 8;
      #pragma unroll
      for (int ks2 = 0; ks2 < 2; ks2++) {
        const int ks = half * 2 + ks2;
        #pragma unroll
        for (int sub = 0; sub < 2; sub++) {
          const int dd = sub * 32 + d;
          union { u16 h[8]; uint4 u; } o;
          #pragma unroll
          for (int j = 0; j < 8; j++) {
            int srow = ks2 * 16 + hi8 + j;
            o.h[j] = *(u16*)(otb + ((srow * 128 + dd * 2) ^ ((srow & 7) << 4)));
          }
          *(uint4*)(dst + (sub * 4 + ks) * 512 + lane * 8) = o.u;
        }
      }
    }
    __builtin_amdgcn_s_barrier();
  }
}

// ============================================================================
// 128x256 bf16 GEMM (output projection), f32 C write
// ============================================================================
__global__ __launch_bounds__(512, 4) void gemm8p(
    const u16* __restrict__ Af, const u16* __restrict__ Bf,
    float* __restrict__ C, int N, int KT, int nbx) {
  __shared__ u16 lds[2 * 24 * 512];
  const int tid = threadIdx.x, lane = tid & 63, w = tid >> 6;
  const int wm = w >> 2, wn = w & 3;
  const int lrow = lane & 15, lg = lane >> 4;
  const int nwg = gridDim.x;
  const int per = nwg >> 3;
  const int swz = ((int)blockIdx.x & 7) * per + ((int)blockIdx.x >> 3);
  const int bm = swz / nbx, bn = swz % nbx;
  const int bm8 = bm * 8, bn16 = bn * 16;
  const int T = KT;

  f32x4 acc[4][4] = {};
  u16* buf0 = lds;
  u16* buf1 = lds + 24 * 512;

  auto stageB = [&](int s, u16* dst) {
    #pragma unroll
    for (int j = 0; j < 2; j++) {
      int ng = w * 2 + j;
      gld16(Bf + ((size_t)(bn16 + ng) * KT + s) * 512 + lane * 8,
            dst + (8 + ng) * 512);
    }
  };
  auto stageA = [&](int s, u16* dst) {
    gld16(Af + ((size_t)(bm8 + w) * KT + s) * 512 + lane * 8,
          dst + w * 512);
  };

  stageB(0, buf0); stageA(0, buf0);
  stageB(1, buf1); stageA(1, buf1);
  asm volatile("s_waitcnt vmcnt(3)" ::: "memory");
  __builtin_amdgcn_s_barrier();

  bfx8 ar[2], br[4];
  for (int t = 0; t < T; t++) {
    u16* rb = (t & 1) ? buf1 : buf0;
    const int s2 = (t + 2 < T) ? t + 2 : 0;
    #pragma unroll
    for (int i = 0; i < 2; i++)
      ar[i] = *(const bfx8*)(rb + (wm * 4 + i) * 512 + lane * 8);
    #pragma unroll
    for (int j = 0; j < 4; j++)
      br[j] = *(const bfx8*)(rb + (8 + wn * 4 + j) * 512 + lane * 8);
    asm volatile("s_waitcnt lgkmcnt(0)" ::: "memory");
    __builtin_amdgcn_s_barrier();
    stageB(s2, rb);
    __builtin_amdgcn_s_setprio(1);
    #pragma unroll
    for (int i = 0; i < 2; i++)
      #pragma unroll
      for (int j = 0; j < 4; j++)
        acc[i][j] = MFMA16(ar[i], br[j], acc[i][j]);
    __builtin_amdgcn_s_setprio(0);
    __builtin_amdgcn_s_barrier();
    #pragma unroll
    for (int i = 0; i < 2; i++)
      ar[i] = *(const bfx8*)(rb + (wm * 4 + 2 + i) * 512 + lane * 8);
    asm volatile("s_waitcnt lgkmcnt(0)" ::: "memory");
    __builtin_amdgcn_s_barrier();
    stageA(s2, rb);
    __builtin_amdgcn_s_setprio(1);
    #pragma unroll
    for (int i = 0; i < 2; i++)
      #pragma unroll
      for (int j = 0; j < 4; j++)
        acc[2 + i][j] = MFMA16(ar[i], br[j], acc[2 + i][j]);
    __builtin_amdgcn_s_setprio(0);
    asm volatile("s_waitcnt vmcnt(3)" ::: "memory");
    __builtin_amdgcn_s_barrier();
  }
  asm volatile("s_waitcnt vmcnt(0)" ::: "memory");

  const int m0 = bm * 128 + wm * 64, n0 = bn * 256 + wn * 64;
  #pragma unroll
  for (int mg = 0; mg < 4; mg++) {
    int row = m0 + mg * 16 + lg * 4;
    #pragma unroll
    for (int ng = 0; ng < 4; ng++) {
      int col = n0 + ng * 16 + lrow;
      float* cp = C + (size_t)row * N + col;
      #pragma unroll
      for (int r = 0; r < 4; r++) cp[(size_t)r * N] = acc[mg][ng][r];
    }
  }
}

// ---------- causal flash attention, GQA — R8 structure + unroll-2 K-loop ----------
// grid (8, H, B), 256 thr. Wave w handles q-tiles {63-qrA, qrA}: exactly 33
// K-tiles per wave. kn prefetch one tile ahead; unroll-2 lets the compiler
// register-rename away the ka<-kn rotation. Pointer-incremented addressing.
__global__ __launch_bounds__(256, 2) void attn_k(
    const u16* __restrict__ Qf, const u16* __restrict__ Kf,
    const u16* __restrict__ Vf, u16* __restrict__ Aof)
{
  __shared__ u16 ot[4][32 * 64];
  const int tid = threadIdx.x, lane = tid & 63, w = tid >> 6;
  const int h = blockIdx.y, b = blockIdx.z;
  const int kvh = h >> 2;
  const int ql = lane & 31, hi = lane >> 5;
  const int qrA = blockIdx.x * 4 + w;     // in [0,32)

  const u16* Qh = Qf + (size_t)(b * 32 + h) * 131072;
  const u16* Kp = Kf + (size_t)(b * 8 + kvh) * 131072 + lane * 8;
  const u16* Vp = Vf + (size_t)(b * 8 + kvh) * 131072 + lane * 8;

  #pragma unroll
  for (int half = 0; half < 2; half++) {
    const int qr = half ? qrA : 63 - qrA;
    const int q0 = qr * 32;
    const int qg = q0 + ql;
    const int nkt = qr / 2 + 1;

    bfx8 qf[4];
    #pragma unroll
    for (int ks = 0; ks < 4; ks++)
      qf[ks] = *(const bfx8*)(Qh + (size_t)qr * 2048 + ks * 512 + lane * 8);

    f32x16 oacc0 = {}, oacc1 = {};
    float m2 = -3.0e38f;
    float lsum = 0.f;

    const u16* Kt = Kp;
    const u16* Vt = Vp;
    bfx8 ka[8];
    #pragma unroll
    for (int i = 0; i < 8; i++)
      ka[i] = *(const bfx8*)(Kt + i * 512);

    #pragma unroll 2
    for (int kt = 0; kt < nkt; kt++) {
      const int kb = kt * 64;
      bfx8 va[8];
      #pragma unroll
      for (int i = 0; i < 8; i++)
        va[i] = *(const bfx8*)(Vt + i * 512);
      f32x16 st0 = {}, st1 = {};
      #pragma unroll
      for (int ks = 0; ks < 4; ks++) {
        st0 = MFMA32(ka[ks], qf[ks], st0);
        st1 = MFMA32(ka[4 + ks], qf[ks], st1);
      }
      const u16* Kn = (kt + 1 < nkt) ? Kt + 4096 : Kp;
      bfx8 kn[8];
      #pragma unroll
      for (int i = 0; i < 8; i++)
        kn[i] = *(const bfx8*)(Kn + i * 512);
      if (kt == nkt - 1) {
        #pragma unroll
        for (int r = 0; r < 16; r++) {
          int crow = (r & 3) + 8 * (r >> 2) + 4 * hi;
          if (kb + crow > qg) st0[r] = -3.0e38f;
          if (kb + 32 + crow > qg) st1[r] = -3.0e38f;
        }
      }
      float mx[16];
      #pragma unroll
      for (int r = 0; r < 16; r++) mx[r] = fmaxf(st0[r], st1[r]);
      #pragma unroll
      for (int s = 8; s > 0; s >>= 1)
        #pragma unroll
        for (int r = 0; r < s; r++) mx[r] = fmaxf(mx[r], mx[r + s]);
      float tm = fmaxf(mx[0], __shfl_xor(mx[0], 32));
      float mnew = fmaxf(m2, tm);
      if (!__all(tm <= m2 + 8.0f)) {
        float corr = exp2f(m2 - mnew);
        lsum *= corr;
        #pragma unroll
        for (int i = 0; i < 16; i++) { oacc0[i] *= corr; oacc1[i] *= corr; }
        m2 = mnew;
      }
      #pragma unroll
      for (int r = 0; r < 16; r++) { st0[r] = exp2f(st0[r] - m2); }
      #pragma unroll
      for (int r = 0; r < 16; r++) { st1[r] = exp2f(st1[r] - m2); }
      float sm[16];
      #pragma unroll
      for (int r = 0; r < 16; r++) sm[r] = st0[r] + st1[r];
      #pragma unroll
      for (int s = 8; s > 0; s >>= 1)
        #pragma unroll
        for (int r = 0; r < s; r++) sm[r] += sm[r + s];
      lsum += sm[0];
      bfx8 pb[4];
      #pragma unroll
      for (int ks = 0; ks < 4; ks++) {
        int o = (ks & 1) * 8;
        unsigned X = cvtpk(ks < 2 ? st0[o + 0] : st1[o + 0], ks < 2 ? st0[o + 1] : st1[o + 1]);
        unsigned Z = cvtpk(ks < 2 ? st0[o + 2] : st1[o + 2], ks < 2 ? st0[o + 3] : st1[o + 3]);
        unsigned Y = cvtpk(ks < 2 ? st0[o + 4] : st1[o + 4], ks < 2 ? st0[o + 5] : st1[o + 5]);
        unsigned W = cvtpk(ks < 2 ? st0[o + 6] : st1[o + 6], ks < 2 ? st0[o + 7] : st1[o + 7]);
        swap32(X, Y);
        swap32(Z, W);
        union { unsigned u[4]; bfx8 v; } uu;
        uu.u[0] = X; uu.u[1] = Z; uu.u[2] = Y; uu.u[3] = W;
        pb[ks] = uu.v;
      }
      #pragma unroll
      for (int ks = 0; ks < 4; ks++) {
        oacc0 = MFMA32(va[ks], pb[ks], oacc0);
        oacc1 = MFMA32(va[4 + ks], pb[ks], oacc1);
      }
      #pragma unroll
      for (int i = 0; i < 8; i++) ka[i] = kn[i];
      Kt += 4096;
      Vt += 4096;
    }
    lsum += __shfl_xor(lsum, 32);
    float inv = 1.f / lsum;
    u16* my = ot[w];
    #pragma unroll
    for (int dt = 0; dt < 2; dt++) {
      #pragma unroll
      for (int g = 0; g < 4; g++) {
        float a0 = (dt ? oacc1[g*4+0] : oacc0[g*4+0]) * inv;
        float a1 = (dt ? oacc1[g*4+1] : oacc0[g*4+1]) * inv;
        float a2 = (dt ? oacc1[g*4+2] : oacc0[g*4+2]) * inv;
        float a3 = (dt ? oacc1[g*4+3] : oacc0[g*4+3]) * inv;
        unsigned w0 = cvtpk(a0, a1), w1 = cvtpk(a2, a3);
        int d = dt * 32 + g * 8 + 4 * hi;
        int byte = (ql * 128 + d * 2) ^ ((ql & 7) << 4);
        *(uint2*)((char*)my + byte) = make_uint2(w0, w1);
      }
    }
    #pragma unroll
    for (int rr = 0; rr < 4; rr++) {
      int q = rr * 8 + (lane >> 3);
      int dk = (lane & 7) * 8;
      int byte = (q * 128 + dk * 2) ^ ((q & 7) << 4);
      uint4 val = *(uint4*)((char*)my + byte);
      int mt = b * 128 + qr * 2 + (q >> 4);
      int ktg = h * 2 + (dk >> 5);
      int lp = (q & 15) + ((dk >> 3) & 3) * 16;
      *(uint4*)(Aof + ((size_t)(mt * 64 + ktg) * 512 + lp * 8)) = val;
    }
  }
}

// ---------- launch ----------
extern "C" void kernel_launch(void* const* d_in, const int* in_sizes, int n_in,
                              void* d_out, int out_size, void* d_ws, size_t ws_size,
                              hipStream_t stream) {
  const float* x    = (const float*)d_in[0];
  const float* cosT = (const float*)d_in[1];
  const float* sinT = (const float*)d_in[2];
  const float* Wq   = (const float*)d_in[3];
  const float* Wk   = (const float*)d_in[4];
  const float* Wv   = (const float*)d_in[5];
  const float* Wo   = (const float*)d_in[6];
  float* out = (float*)d_out;
  char* ws = (char*)d_ws;

  u16* Af   = (u16*)(ws);                    // 16 MB (x frags)
  u16* Bqkv = (u16*)(ws + 16777216);         // 12 MB
  u16* Bwo  = (u16*)(ws + 29360128);         //  8 MB
  u16* Qf   = (u16*)(ws + 37748736);         // 16 MB
  u16* Kf   = (u16*)(ws + 54525952);         //  4 MB
  u16* Vf   = (u16*)(ws + 58720256);         //  4 MB
  u16* Aof  = (u16*)(ws + 62914560);         // 16 MB

  afrag_k<<<4096, 256, 0, stream>>>(x, Af);
  bfrag_k<<<dim3(32, 64), 256, 0, stream>>>(Wq, Bqkv, 2048, 0);
  bfrag_k<<<dim3(8, 64), 256, 0, stream>>>(Wk, Bqkv, 512, 128);
  bfrag_k<<<dim3(8, 64), 256, 0, stream>>>(Wv, Bqkv, 512, 160);
  bfrag_k<<<dim3(32, 64), 256, 0, stream>>>(Wo, Bwo, 2048, 0);

  gemm_qkv<<<384, 512, 0, stream>>>(Af, Bqkv, cosT, sinT, Qf, Kf, Vf);

  attn_k<<<dim3(8, 32, 2), 256, 0, stream>>>(Qf, Kf, Vf, Aof);

  gemm8p<<<256, 512, 0, stream>>>(Aof, Bwo, out, 2048, 64, 8);
}

// Round 11
// 196.649 us; speedup vs baseline: 1.1548x; 1.0160x over previous
//
#include <hip/hip_runtime.h>

typedef unsigned short u16;
typedef __bf16 bfx8 __attribute__((ext_vector_type(8)));
typedef float f32x4 __attribute__((ext_vector_type(4)));
typedef float f32x16 __attribute__((ext_vector_type(16)));

#define MFMA16(a,b,c) __builtin_amdgcn_mfma_f32_16x16x32_bf16(a,b,c,0,0,0)
#define MFMA32(a,b,c) __builtin_amdgcn_mfma_f32_32x32x16_bf16(a,b,c,0,0,0)

// ---------- helpers ----------
__device__ __forceinline__ u16 f2bf(float f) {
  union { float f; unsigned u; } v; v.f = f;
  unsigned r = v.u + 0x7fffu + ((v.u >> 16) & 1u);   // RNE
  return (u16)(r >> 16);
}

__device__ __forceinline__ unsigned cvtpk(float lo, float hi) {
  unsigned r;
  asm("v_cvt_pk_bf16_f32 %0, %1, %2" : "=v"(r) : "v"(lo), "v"(hi));
  return r;
}

__device__ __forceinline__ void swap32(unsigned &a, unsigned &b) {
  asm("v_permlane32_swap_b32 %0, %1" : "+v"(a), "+v"(b));
}

__device__ __forceinline__ void gld16(const void* g, void* l) {
  __builtin_amdgcn_global_load_lds(
      (const __attribute__((address_space(1))) unsigned int*)g,
      (__attribute__((address_space(3))) unsigned int*)l, 16, 0, 0);
}

// ============================================================================
// Fragment-linear layouts:
//   Xf[(rowgrp * KT + kgrp) * 512 + lane * 8 + j]
//     holds X[rowgrp*16 + (lane&15)][kgrp*32 + (lane>>4)*8 + j]   (KT = K/32)
// ============================================================================

// ---------- x [4096][2048] f32 -> Af fragment-linear bf16 ----------
__global__ void afrag_k(const float* __restrict__ in, u16* __restrict__ Af) {
  int i = blockIdx.x * 256 + threadIdx.x;
  int sm = i >> 8, d0 = (i & 255) * 8;
  const float* p = in + (size_t)sm * 2048 + d0;
  float4 a = *(const float4*)p;
  float4 b = *(const float4*)(p + 4);
  union { u16 h[8]; uint4 u; } o;
  o.h[0]=f2bf(a.x); o.h[1]=f2bf(a.y); o.h[2]=f2bf(a.z); o.h[3]=f2bf(a.w);
  o.h[4]=f2bf(b.x); o.h[5]=f2bf(b.y); o.h[6]=f2bf(b.z); o.h[7]=f2bf(b.w);
  int mt = sm >> 4, kt = d0 >> 5, lp = (sm & 15) + ((d0 >> 3) & 3) * 16;
  *(uint4*)(Af + ((size_t)(mt * 64 + kt) * 512 + lp * 8)) = o.u;
}

// ---------- W [2048 K][N] f32 -> Bf fragment-linear bf16 (B^T[n][k]) ----------
__global__ void bfrag_k(const float* __restrict__ W, u16* __restrict__ Bf,
                        int N, int ntoff) {
  __shared__ float tile[32][72];
  int nb = blockIdx.x, kb = blockIdx.y;
  int t = threadIdx.x;
  int r = t >> 3, c8 = (t & 7) * 8;
  const float* src = W + (size_t)(kb * 32 + r) * N + nb * 64 + c8;
  *(float4*)&tile[r][c8]     = *(const float4*)src;
  *(float4*)&tile[r][c8 + 4] = *(const float4*)(src + 4);
  __syncthreads();
  int fb = t >> 6, l = t & 63;
  int nn = fb * 16 + (l & 15), k0 = (l >> 4) * 8;
  union { u16 h[8]; uint4 u; } o;
  #pragma unroll
  for (int j = 0; j < 8; j++) o.h[j] = f2bf(tile[k0 + j][nn]);
  *(uint4*)(Bf + ((size_t)((ntoff + nb * 4 + fb) * 64 + kb) * 512 + l * 8)) = o.u;
}

// ============================================================================
// QKV GEMM 64x256, 4 waves (wave = 64 rows x one 64-col head), BK=32,
// counted vmcnt(5) — FUSED RoPE + frag epilogue. grid = 64*12 = 768 = 3/CU.
// LDS 40KB: 2 buf x (A:0..3, B:4..19) x 1KB.
// ============================================================================
__global__ __launch_bounds__(256, 3) void gemm_qkv(
    const u16* __restrict__ Af, const u16* __restrict__ Bf,
    const float* __restrict__ cosT, const float* __restrict__ sinT,
    u16* __restrict__ Qf, u16* __restrict__ Kf, u16* __restrict__ Vf) {
  __shared__ u16 lds[2 * 20 * 512];
  const int tid = threadIdx.x, lane = tid & 63, w = tid >> 6;
  const int lrow = lane & 15, lg = lane >> 4;
  const int nwg = gridDim.x;
  const int per = nwg >> 3;
  const int swz = ((int)blockIdx.x & 7) * per + ((int)blockIdx.x >> 3);
  const int bm = swz / 12, bn = swz % 12;
  const int bm4 = bm * 4, bn16 = bn * 16;
  const int KT = 64;

  f32x4 acc[4][4] = {};
  u16* buf0 = lds;
  u16* buf1 = lds + 20 * 512;

  auto stageB = [&](int s, u16* dst) {
    #pragma unroll
    for (int j = 0; j < 4; j++) {
      int ng = w * 4 + j;
      gld16(Bf + ((size_t)(bn16 + ng) * KT + s) * 512 + lane * 8,
            dst + (4 + ng) * 512);
    }
  };
  auto stageA = [&](int s, u16* dst) {
    gld16(Af + ((size_t)(bm4 + w) * KT + s) * 512 + lane * 8,
          dst + w * 512);
  };

  stageB(0, buf0); stageA(0, buf0);
  stageB(1, buf1); stageA(1, buf1);
  asm volatile("s_waitcnt vmcnt(5)" ::: "memory");
  __builtin_amdgcn_s_barrier();

  bfx8 ar[2], br[4];
  for (int t = 0; t < KT; t++) {
    u16* rb = (t & 1) ? buf1 : buf0;
    const int s2 = (t + 2 < KT) ? t + 2 : 0;
    // ---- phase 0: rows 0-31 ----
    #pragma unroll
    for (int i = 0; i < 2; i++)
      ar[i] = *(const bfx8*)(rb + i * 512 + lane * 8);
    #pragma unroll
    for (int j = 0; j < 4; j++)
      br[j] = *(const bfx8*)(rb + (4 + w * 4 + j) * 512 + lane * 8);
    asm volatile("s_waitcnt lgkmcnt(0)" ::: "memory");
    __builtin_amdgcn_s_barrier();
    stageB(s2, rb);
    __builtin_amdgcn_s_setprio(1);
    #pragma unroll
    for (int i = 0; i < 2; i++)
      #pragma unroll
      for (int j = 0; j < 4; j++)
        acc[i][j] = MFMA16(ar[i], br[j], acc[i][j]);
    __builtin_amdgcn_s_setprio(0);
    __builtin_amdgcn_s_barrier();
    // ---- phase 1: rows 32-63 ----
    #pragma unroll
    for (int i = 0; i < 2; i++)
      ar[i] = *(const bfx8*)(rb + (2 + i) * 512 + lane * 8);
    asm volatile("s_waitcnt lgkmcnt(0)" ::: "memory");
    __builtin_amdgcn_s_barrier();
    stageA(s2, rb);
    __builtin_amdgcn_s_setprio(1);
    #pragma unroll
    for (int i = 0; i < 2; i++)
      #pragma unroll
      for (int j = 0; j < 4; j++)
        acc[2 + i][j] = MFMA16(ar[i], br[j], acc[2 + i][j]);
    __builtin_amdgcn_s_setprio(0);
    asm volatile("s_waitcnt vmcnt(5)" ::: "memory");
    __builtin_amdgcn_s_barrier();
  }
  asm volatile("s_waitcnt vmcnt(0)" ::: "memory");
  __builtin_amdgcn_s_barrier();   // gemm LDS now reusable

  // ---------------- fused epilogue ----------------
  const int hh = bn * 4 + w;                // global head slot [0,48)
  const int m0 = bm * 64;
  u16* otw = lds + w * 2048;                // per-wave 4KB slice
  char* otb = (char*)otw;

  #pragma unroll
  for (int half = 0; half < 2; half++) {
    const int rowbase = m0 + half * 32;
    const int bb = rowbase >> 11;
    const int s0 = rowbase & 2047;
    if (hh < 40) {
      const float qsc = (hh < 32) ? 0.18033688f : 1.0f;
      #pragma unroll
      for (int mgl = 0; mgl < 2; mgl++) {
        const int mg = half * 2 + mgl;
        #pragma unroll
        for (int ng = 0; ng < 2; ng++) {
          const int d1 = ng * 16 + lrow;
          #pragma unroll
          for (int r = 0; r < 4; r++) {
            int s = s0 + mgl * 16 + lg * 4 + r;
            float a  = acc[mg][ng][r];
            float a2 = acc[mg][ng + 2][r];
            float c1 = cosT[s * 64 + d1],      s1v = sinT[s * 64 + d1];
            float c2 = cosT[s * 64 + d1 + 32], s2v = sinT[s * 64 + d1 + 32];
            float o1 = (a * c1 - a2 * s1v) * qsc;
            float o2 = (a2 * c2 + a * s2v) * qsc;
            int srow = mgl * 16 + lg * 4 + r;
            int swzb = (srow & 7) << 4;
            *(u16*)(otb + ((srow * 128 + d1 * 2) ^ swzb)) = f2bf(o1);
            *(u16*)(otb + ((srow * 128 + (d1 + 32) * 2) ^ swzb)) = f2bf(o2);
          }
        }
      }
      const int qt = s0 >> 5;
      u16* dst = (hh < 32)
          ? Qf + ((size_t)(bb * 32 + hh) * 64 + qt) * 2048
          : Kf + ((size_t)(bb * 8 + (hh - 32)) * 64 + qt) * 2048;
      const int srw = lane & 31;
      const int d0 = (lane >> 5) * 8;
      #pragma unroll
      for (int ks = 0; ks < 4; ks++) {
        int byte = ((srw * 128 + (ks * 16 + d0) * 2)) ^ ((srw & 7) << 4);
        uint4 v = *(uint4*)(otb + byte);
        *(uint4*)(dst + ks * 512 + lane * 8) = v;
      }
    } else {
      #pragma unroll
      for (int mgl = 0; mgl < 2; mgl++) {
        const int mg = half * 2 + mgl;
        #pragma unroll
        for (int ng = 0; ng < 4; ng++) {
          const int d = ng * 16 + lrow;
          #pragma unroll
          for (int r = 0; r < 4; r++) {
            int srow = mgl * 16 + lg * 4 + r;
            *(u16*)(otb + ((srow * 128 + d * 2) ^ ((srow & 7) << 4))) =
                f2bf(acc[mg][ng][r]);
          }
        }
      }
      const int kt = s0 >> 6;
      const int g = hh - 40;
      u16* dst = Vf + ((size_t)(bb * 8 + g) * 32 + kt) * 4096;
      const int d = lane & 31;
      const int hi8 = (lane >> 5) * 8;
      #pragma unroll
      for (int ks2 = 0; ks2 < 2; ks2++) {
        const int ks = half * 2 + ks2;
        #pragma unroll
        for (int sub = 0; sub < 2; sub++) {
          const int dd = sub * 32 + d;
          union { u16 h[8]; uint4 u; } o;
          #pragma unroll
          for (int j = 0; j < 8; j++) {
            int srow = ks2 * 16 + hi8 + j;
            o.h[j] = *(u16*)(otb + ((srow * 128 + dd * 2) ^ ((srow & 7) << 4)));
          }
          *(uint4*)(dst + (sub * 4 + ks) * 512 + lane * 8) = o.u;
        }
      }
    }
    __builtin_amdgcn_s_barrier();
  }
}

// ============================================================================
// Output GEMM 64x256, 4 waves (wave = 64x64), BK=32, counted vmcnt(5),
// f32 C write. grid = 64*8 = 512 = 2/CU (3-block capacity -> overlap).
// ============================================================================
__global__ __launch_bounds__(256, 3) void gemm8p(
    const u16* __restrict__ Af, const u16* __restrict__ Bf,
    float* __restrict__ C, int N, int KT, int nbx) {
  __shared__ u16 lds[2 * 20 * 512];
  const int tid = threadIdx.x, lane = tid & 63, w = tid >> 6;
  const int lrow = lane & 15, lg = lane >> 4;
  const int nwg = gridDim.x;
  const int per = nwg >> 3;
  const int swz = ((int)blockIdx.x & 7) * per + ((int)blockIdx.x >> 3);
  const int bm = swz / nbx, bn = swz % nbx;
  const int bm4 = bm * 4, bn16 = bn * 16;
  const int T = KT;

  f32x4 acc[4][4] = {};
  u16* buf0 = lds;
  u16* buf1 = lds + 20 * 512;

  auto stageB = [&](int s, u16* dst) {
    #pragma unroll
    for (int j = 0; j < 4; j++) {
      int ng = w * 4 + j;
      gld16(Bf + ((size_t)(bn16 + ng) * KT + s) * 512 + lane * 8,
            dst + (4 + ng) * 512);
    }
  };
  auto stageA = [&](int s, u16* dst) {
    gld16(Af + ((size_t)(bm4 + w) * KT + s) * 512 + lane * 8,
          dst + w * 512);
  };

  stageB(0, buf0); stageA(0, buf0);
  stageB(1, buf1); stageA(1, buf1);
  asm volatile("s_waitcnt vmcnt(5)" ::: "memory");
  __builtin_amdgcn_s_barrier();

  bfx8 ar[2], br[4];
  for (int t = 0; t < T; t++) {
    u16* rb = (t & 1) ? buf1 : buf0;
    const int s2 = (t + 2 < T) ? t + 2 : 0;
    #pragma unroll
    for (int i = 0; i < 2; i++)
      ar[i] = *(const bfx8*)(rb + i * 512 + lane * 8);
    #pragma unroll
    for (int j = 0; j < 4; j++)
      br[j] = *(const bfx8*)(rb + (4 + w * 4 + j) * 512 + lane * 8);
    asm volatile("s_waitcnt lgkmcnt(0)" ::: "memory");
    __builtin_amdgcn_s_barrier();
    stageB(s2, rb);
    __builtin_amdgcn_s_setprio(1);
    #pragma unroll
    for (int i = 0; i < 2; i++)
      #pragma unroll
      for (int j = 0; j < 4; j++)
        acc[i][j] = MFMA16(ar[i], br[j], acc[i][j]);
    __builtin_amdgcn_s_setprio(0);
    __builtin_amdgcn_s_barrier();
    #pragma unroll
    for (int i = 0; i < 2; i++)
      ar[i] = *(const bfx8*)(rb + (2 + i) * 512 + lane * 8);
    asm volatile("s_waitcnt lgkmcnt(0)" ::: "memory");
    __builtin_amdgcn_s_barrier();
    stageA(s2, rb);
    __builtin_amdgcn_s_setprio(1);
    #pragma unroll
    for (int i = 0; i < 2; i++)
      #pragma unroll
      for (int j = 0; j < 4; j++)
        acc[2 + i][j] = MFMA16(ar[i], br[j], acc[2 + i][j]);
    __builtin_amdgcn_s_setprio(0);
    asm volatile("s_waitcnt vmcnt(5)" ::: "memory");
    __builtin_amdgcn_s_barrier();
  }
  asm volatile("s_waitcnt vmcnt(0)" ::: "memory");

  const int m0 = bm * 64, n0 = bn * 256 + w * 64;
  #pragma unroll
  for (int mg = 0; mg < 4; mg++) {
    int row = m0 + mg * 16 + lg * 4;
    #pragma unroll
    for (int ng = 0; ng < 4; ng++) {
      int col = n0 + ng * 16 + lrow;
      float* cp = C + (size_t)row * N + col;
      #pragma unroll
      for (int r = 0; r < 4; r++) cp[(size_t)r * N] = acc[mg][ng][r];
    }
  }
}

// ---------- causal flash attention, GQA — R10 structure (frozen) ----------
__global__ __launch_bounds__(256, 2) void attn_k(
    const u16* __restrict__ Qf, const u16* __restrict__ Kf,
    const u16* __restrict__ Vf, u16* __restrict__ Aof)
{
  __shared__ u16 ot[4][32 * 64];
  const int tid = threadIdx.x, lane = tid & 63, w = tid >> 6;
  const int h = blockIdx.y, b = blockIdx.z;
  const int kvh = h >> 2;
  const int ql = lane & 31, hi = lane >> 5;
  const int qrA = blockIdx.x * 4 + w;     // in [0,32)

  const u16* Qh = Qf + (size_t)(b * 32 + h) * 131072;
  const u16* Kp = Kf + (size_t)(b * 8 + kvh) * 131072 + lane * 8;
  const u16* Vp = Vf + (size_t)(b * 8 + kvh) * 131072 + lane * 8;

  #pragma unroll
  for (int half = 0; half < 2; half++) {
    const int qr = half ? qrA : 63 - qrA;
    const int q0 = qr * 32;
    const int qg = q0 + ql;
    const int nkt = qr / 2 + 1;

    bfx8 qf[4];
    #pragma unroll
    for (int ks = 0; ks < 4; ks++)
      qf[ks] = *(const bfx8*)(Qh + (size_t)qr * 2048 + ks * 512 + lane * 8);

    f32x16 oacc0 = {}, oacc1 = {};
    float m2 = -3.0e38f;
    float lsum = 0.f;

    const u16* Kt = Kp;
    const u16* Vt = Vp;
    bfx8 ka[8];
    #pragma unroll
    for (int i = 0; i < 8; i++)
      ka[i] = *(const bfx8*)(Kt + i * 512);

    #pragma unroll 2
    for (int kt = 0; kt < nkt; kt++) {
      const int kb = kt * 64;
      bfx8 va[8];
      #pragma unroll
      for (int i = 0; i < 8; i++)
        va[i] = *(const bfx8*)(Vt + i * 512);
      f32x16 st0 = {}, st1 = {};
      #pragma unroll
      for (int ks = 0; ks < 4; ks++) {
        st0 = MFMA32(ka[ks], qf[ks], st0);
        st1 = MFMA32(ka[4 + ks], qf[ks], st1);
      }
      const u16* Kn = (kt + 1 < nkt) ? Kt + 4096 : Kp;
      bfx8 kn[8];
      #pragma unroll
      for (int i = 0; i < 8; i++)
        kn[i] = *(const bfx8*)(Kn + i * 512);
      if (kt == nkt - 1) {
        #pragma unroll
        for (int r = 0; r < 16; r++) {
          int crow = (r & 3) + 8 * (r >> 2) + 4 * hi;
          if (kb + crow > qg) st0[r] = -3.0e38f;
          if (kb + 32 + crow > qg) st1[r] = -3.0e38f;
        }
      }
      float mx[16];
      #pragma unroll
      for (int r = 0; r < 16; r++) mx[r] = fmaxf(st0[r], st1[r]);
      #pragma unroll
      for (int s = 8; s > 0; s >>= 1)
        #pragma unroll
        for (int r = 0; r < s; r++) mx[r] = fmaxf(mx[r], mx[r + s]);
      float tm = fmaxf(mx[0], __shfl_xor(mx[0], 32));
      float mnew = fmaxf(m2, tm);
      if (!__all(tm <= m2 + 8.0f)) {
        float corr = exp2f(m2 - mnew);
        lsum *= corr;
        #pragma unroll
        for (int i = 0; i < 16; i++) { oacc0[i] *= corr; oacc1[i] *= corr; }
        m2 = mnew;
      }
      #pragma unroll
      for (int r = 0; r < 16; r++) { st0[r] = exp2f(st0[r] - m2); }
      #pragma unroll
      for (int r = 0; r < 16; r++) { st1[r] = exp2f(st1[r] - m2); }
      float sm[16];
      #pragma unroll
      for (int r = 0; r < 16; r++) sm[r] = st0[r] + st1[r];
      #pragma unroll
      for (int s = 8; s > 0; s >>= 1)
        #pragma unroll
        for (int r = 0; r < s; r++) sm[r] += sm[r + s];
      lsum += sm[0];
      bfx8 pb[4];
      #pragma unroll
      for (int ks = 0; ks < 4; ks++) {
        int o = (ks & 1) * 8;
        unsigned X = cvtpk(ks < 2 ? st0[o + 0] : st1[o + 0], ks < 2 ? st0[o + 1] : st1[o + 1]);
        unsigned Z = cvtpk(ks < 2 ? st0[o + 2] : st1[o + 2], ks < 2 ? st0[o + 3] : st1[o + 3]);
        unsigned Y = cvtpk(ks < 2 ? st0[o + 4] : st1[o + 4], ks < 2 ? st0[o + 5] : st1[o + 5]);
        unsigned W = cvtpk(ks < 2 ? st0[o + 6] : st1[o + 6], ks < 2 ? st0[o + 7] : st1[o + 7]);
        swap32(X, Y);
        swap32(Z, W);
        union { unsigned u[4]; bfx8 v; } uu;
        uu.u[0] = X; uu.u[1] = Z; uu.u[2] = Y; uu.u[3] = W;
        pb[ks] = uu.v;
      }
      #pragma unroll
      for (int ks = 0; ks < 4; ks++) {
        oacc0 = MFMA32(va[ks], pb[ks], oacc0);
        oacc1 = MFMA32(va[4 + ks], pb[ks], oacc1);
      }
      #pragma unroll
      for (int i = 0; i < 8; i++) ka[i] = kn[i];
      Kt += 4096;
      Vt += 4096;
    }
    lsum += __shfl_xor(lsum, 32);
    float inv = 1.f / lsum;
    u16* my = ot[w];
    #pragma unroll
    for (int dt = 0; dt < 2; dt++) {
      #pragma unroll
      for (int g = 0; g < 4; g++) {
        float a0 = (dt ? oacc1[g*4+0] : oacc0[g*4+0]) * inv;
        float a1 = (dt ? oacc1[g*4+1] : oacc0[g*4+1]) * inv;
        float a2 = (dt ? oacc1[g*4+2] : oacc0[g*4+2]) * inv;
        float a3 = (dt ? oacc1[g*4+3] : oacc0[g*4+3]) * inv;
        unsigned w0 = cvtpk(a0, a1), w1 = cvtpk(a2, a3);
        int d = dt * 32 + g * 8 + 4 * hi;
        int byte = (ql * 128 + d * 2) ^ ((ql & 7) << 4);
        *(uint2*)((char*)my + byte) = make_uint2(w0, w1);
      }
    }
    #pragma unroll
    for (int rr = 0; rr < 4; rr++) {
      int q = rr * 8 + (lane >> 3);
      int dk = (lane & 7) * 8;
      int byte = (q * 128 + dk * 2) ^ ((q & 7) << 4);
      uint4 val = *(uint4*)((char*)my + byte);
      int mt = b * 128 + qr * 2 + (q >> 4);
      int ktg = h * 2 + (dk >> 5);
      int lp = (q & 15) + ((dk >> 3) & 3) * 16;
      *(uint4*)(Aof + ((size_t)(mt * 64 + ktg) * 512 + lp * 8)) = val;
    }
  }
}

// ---------- launch ----------
extern "C" void kernel_launch(void* const* d_in, const int* in_sizes, int n_in,
                              void* d_out, int out_size, void* d_ws, size_t ws_size,
                              hipStream_t stream) {
  const float* x    = (const float*)d_in[0];
  const float* cosT = (const float*)d_in[1];
  const float* sinT = (const float*)d_in[2];
  const float* Wq   = (const float*)d_in[3];
  const float* Wk   = (const float*)d_in[4];
  const float* Wv   = (const float*)d_in[5];
  const float* Wo   = (const float*)d_in[6];
  float* out = (float*)d_out;
  char* ws = (char*)d_ws;

  u16* Af   = (u16*)(ws);                    // 16 MB (x frags)
  u16* Bqkv = (u16*)(ws + 16777216);         // 12 MB
  u16* Bwo  = (u16*)(ws + 29360128);         //  8 MB
  u16* Qf   = (u16*)(ws + 37748736);         // 16 MB
  u16* Kf   = (u16*)(ws + 54525952);         //  4 MB
  u16* Vf   = (u16*)(ws + 58720256);         //  4 MB
  u16* Aof  = (u16*)(ws + 62914560);         // 16 MB

  afrag_k<<<4096, 256, 0, stream>>>(x, Af);
  bfrag_k<<<dim3(32, 64), 256, 0, stream>>>(Wq, Bqkv, 2048, 0);
  bfrag_k<<<dim3(8, 64), 256, 0, stream>>>(Wk, Bqkv, 512, 128);
  bfrag_k<<<dim3(8, 64), 256, 0, stream>>>(Wv, Bqkv, 512, 160);
  bfrag_k<<<dim3(32, 64), 256, 0, stream>>>(Wo, Bwo, 2048, 0);

  gemm_qkv<<<768, 256, 0, stream>>>(Af, Bqkv, cosT, sinT, Qf, Kf, Vf);

  attn_k<<<dim3(8, 32, 2), 256, 0, stream>>>(Qf, Kf, Vf, Aof);

  gemm8p<<<512, 256, 0, stream>>>(Aof, Bwo, out, 2048, 64, 8);
}